// Round 1
// baseline (2315.556 us; speedup 1.0000x reference)
//
#include <hip/hip_runtime.h>

#define N_NODES 50000
#define N_INC   300000
#define DIM     256
#define M_EDGES 20000
#define NEG_SLOPE 0.2f
#define BN_EPS  1e-5f

// Order-preserving float<->uint map for atomicMax on signed floats.
__device__ __forceinline__ unsigned fmap(float x) {
    unsigned s = __float_as_uint(x);
    return (s & 0x80000000u) ? ~s : (s | 0x80000000u);
}
__device__ __forceinline__ float funmap(unsigned u) {
    unsigned s = (u & 0x80000000u) ? (u ^ 0x80000000u) : ~u;
    return __uint_as_float(s);
}

// ---------------- GEMM: C[M,256] = A[M,256] @ B[256,256], fp32 ----------------
#define BM 64
#define BN 64
#define BK 16
__global__ __launch_bounds__(256) void gemm_kernel(
    const float* __restrict__ A, const float* __restrict__ B,
    float* __restrict__ C, int Mrows)
{
    __shared__ float As[BK][BM + 4];   // k-major (transposed) to allow float4 reads
    __shared__ float Bs[BK][BN + 4];
    int tid = threadIdx.x;
    int tx = tid & 15, ty = tid >> 4;
    int bm = blockIdx.x * BM, bn = blockIdx.y * BN;
    float acc[4][4] = {};

    for (int k0 = 0; k0 < DIM; k0 += BK) {
        {   // A tile: 64 rows x 16 k; thread loads float4 along k
            int r = tid >> 2, kk = (tid & 3) * 4;
            int row = bm + r;
            float4 v = make_float4(0.f, 0.f, 0.f, 0.f);
            if (row < Mrows) v = *(const float4*)(A + (size_t)row * DIM + k0 + kk);
            As[kk + 0][r] = v.x; As[kk + 1][r] = v.y;
            As[kk + 2][r] = v.z; As[kk + 3][r] = v.w;
        }
        {   // B tile: 16 k x 64 cols
            int kr = tid >> 4, c4 = (tid & 15) * 4;
            float4 v = *(const float4*)(B + (size_t)(k0 + kr) * DIM + bn + c4);
            *(float4*)&Bs[kr][c4] = v;
        }
        __syncthreads();
        #pragma unroll
        for (int kk = 0; kk < BK; ++kk) {
            float4 a4 = *(const float4*)&As[kk][ty * 4];
            float4 b4 = *(const float4*)&Bs[kk][tx * 4];
            float a[4] = {a4.x, a4.y, a4.z, a4.w};
            float b[4] = {b4.x, b4.y, b4.z, b4.w};
            #pragma unroll
            for (int i = 0; i < 4; ++i)
                #pragma unroll
                for (int j = 0; j < 4; ++j)
                    acc[i][j] = fmaf(a[i], b[j], acc[i][j]);
        }
        __syncthreads();
    }
    #pragma unroll
    for (int i = 0; i < 4; ++i) {
        int row = bm + ty * 4 + i;
        if (row < Mrows) {
            float4 v = make_float4(acc[i][0], acc[i][1], acc[i][2], acc[i][3]);
            *(float4*)(C + (size_t)row * DIM + bn + tx * 4) = v;
        }
    }
}

// ------------- attention: one wave per incidence -------------
__global__ __launch_bounds__(256) void attn_kernel(
    const float* __restrict__ xw, const int* __restrict__ node_idx,
    const int* __restrict__ edge_idx, const float* __restrict__ att,
    float* __restrict__ alpha, unsigned* __restrict__ amax_u)
{
    int e = blockIdx.x * 4 + (threadIdx.x >> 6);
    if (e >= N_INC) return;
    int lane = threadIdx.x & 63;
    int n = node_idx[e], h = edge_idx[e];
    float4 xi = *(const float4*)(xw + (size_t)n * DIM + lane * 4);
    float4 xj = *(const float4*)(xw + (size_t)h * DIM + lane * 4);
    float4 a1 = *(const float4*)(att + lane * 4);
    float4 a2 = *(const float4*)(att + DIM + lane * 4);
    float s = xi.x * a1.x + xi.y * a1.y + xi.z * a1.z + xi.w * a1.w
            + xj.x * a2.x + xj.y * a2.y + xj.z * a2.z + xj.w * a2.w;
    #pragma unroll
    for (int off = 32; off >= 1; off >>= 1) s += __shfl_down(s, off);
    if (lane == 0) {
        s = s > 0.f ? s : NEG_SLOPE * s;      // leaky_relu
        alpha[e] = s;
        atomicMax(amax_u + n, fmap(s));
    }
}

// ------------- exp + segment sums + degrees: one thread per incidence -------------
__global__ void expsum_kernel(
    const int* __restrict__ node_idx, const int* __restrict__ edge_idx,
    float* __restrict__ alpha, const unsigned* __restrict__ amax_u,
    float* __restrict__ esum, float* __restrict__ Dn, float* __restrict__ Be)
{
    int e = blockIdx.x * blockDim.x + threadIdx.x;
    if (e >= N_INC) return;
    int n = node_idx[e];
    float am = funmap(amax_u[n]);      // node has >=1 incidence by construction
    float ev = expf(alpha[e] - am);
    alpha[e] = ev;                     // store unnormalized exp
    atomicAdd(esum + n, ev);
    atomicAdd(Dn + n, 1.f);
    atomicAdd(Be + edge_idx[e], 1.f);
}

// ------------- stage 1: node -> hyperedge scatter, one wave per incidence -------------
__global__ __launch_bounds__(256) void stage1_kernel(
    const float* __restrict__ xw, const int* __restrict__ node_idx,
    const int* __restrict__ edge_idx, const float* __restrict__ alpha,
    const float* __restrict__ esum, const float* __restrict__ Be,
    float* __restrict__ edge_feat)
{
    int e = blockIdx.x * 4 + (threadIdx.x >> 6);
    if (e >= N_INC) return;
    int lane = threadIdx.x & 63;
    int n = node_idx[e], h = edge_idx[e];
    float w = alpha[e] / (esum[n] + 1e-16f) / Be[h];
    float4 v = *(const float4*)(xw + (size_t)n * DIM + lane * 4);
    float* dst = edge_feat + (size_t)h * DIM + lane * 4;
    atomicAdd(dst + 0, w * v.x);
    atomicAdd(dst + 1, w * v.y);
    atomicAdd(dst + 2, w * v.z);
    atomicAdd(dst + 3, w * v.w);
}

// ------------- stage 2: hyperedge -> node scatter, one wave per incidence -------------
__global__ __launch_bounds__(256) void stage2_kernel(
    const float* __restrict__ edge_feat, const int* __restrict__ node_idx,
    const int* __restrict__ edge_idx, const float* __restrict__ alpha,
    const float* __restrict__ esum, const float* __restrict__ Dn,
    float* __restrict__ outacc)
{
    int e = blockIdx.x * 4 + (threadIdx.x >> 6);
    if (e >= N_INC) return;
    int lane = threadIdx.x & 63;
    int n = node_idx[e], h = edge_idx[e];
    float w = alpha[e] / (esum[n] + 1e-16f) / Dn[n];
    float4 v = *(const float4*)(edge_feat + (size_t)h * DIM + lane * 4);
    float* dst = outacc + (size_t)n * DIM + lane * 4;
    atomicAdd(dst + 0, w * v.x);
    atomicAdd(dst + 1, w * v.y);
    atomicAdd(dst + 2, w * v.z);
    atomicAdd(dst + 3, w * v.w);
}

// ------------- BN column stats: sum and sumsq per column -------------
__global__ __launch_bounds__(256) void stats_kernel(
    const float* __restrict__ outacc, const float* __restrict__ bias,
    float* __restrict__ stats)
{
    int c = threadIdx.x;
    float b = bias[c];
    int rows_per = (N_NODES + gridDim.x - 1) / gridDim.x;
    int r0 = blockIdx.x * rows_per;
    int r1 = min(r0 + rows_per, N_NODES);
    float sum = 0.f, sq = 0.f;
    for (int r = r0; r < r1; ++r) {
        float v = outacc[(size_t)r * DIM + c] + b;
        sum += v; sq += v * v;
    }
    atomicAdd(stats + c, sum);
    atomicAdd(stats + DIM + c, sq);
}

// ------------- BN apply + ELU, in place -------------
__global__ void bn_kernel(
    float* __restrict__ out, const float* __restrict__ bias,
    const float* __restrict__ gamma, const float* __restrict__ beta,
    const float* __restrict__ stats)
{
    int i = blockIdx.x * blockDim.x + threadIdx.x;
    if (i >= N_NODES * DIM) return;
    int c = i & (DIM - 1);
    float mu = stats[c] * (1.f / N_NODES);
    float var = stats[DIM + c] * (1.f / N_NODES) - mu * mu;
    float v = out[i] + bias[c];
    v = gamma[c] * (v - mu) * rsqrtf(var + BN_EPS) + beta[c];
    out[i] = v > 0.f ? v : expm1f(v);   // ELU, alpha=1
}

extern "C" void kernel_launch(void* const* d_in, const int* in_sizes, int n_in,
                              void* d_out, int out_size, void* d_ws, size_t ws_size,
                              hipStream_t stream)
{
    const float* x        = (const float*)d_in[0];
    const int*   node_idx = (const int*)d_in[1];
    const int*   edge_idx = (const int*)d_in[2];
    // d_in[3] = num_hyperedges (fixed 20000)
    const float* W        = (const float*)d_in[4];
    const float* att      = (const float*)d_in[5];
    const float* bias     = (const float*)d_in[6];
    const float* gamma    = (const float*)d_in[7];
    const float* beta     = (const float*)d_in[8];
    float* out = (float*)d_out;

    // workspace layout (floats)
    float*    edge_feat = (float*)d_ws;                       // M*DIM
    float*    alpha     = edge_feat + (size_t)M_EDGES * DIM;  // N_INC
    unsigned* amax_u    = (unsigned*)(alpha + N_INC);         // N_NODES
    float*    esum      = (float*)(amax_u + N_NODES);         // N_NODES
    float*    Dn        = esum + N_NODES;                     // N_NODES
    float*    Be        = Dn + N_NODES;                       // M_EDGES
    float*    stats     = Be + M_EDGES;                       // 2*DIM
    size_t ws_bytes = ((size_t)M_EDGES * DIM + N_INC + 3 * (size_t)N_NODES
                       + M_EDGES + 2 * DIM) * sizeof(float);

    hipMemsetAsync(d_ws, 0, ws_bytes, stream);   // zeros; amax_u=0 is a valid -inf sentinel

    // xw lives in d_out until stage2 needs it as accumulator
    gemm_kernel<<<dim3((N_NODES + BM - 1) / BM, DIM / BN), 256, 0, stream>>>(x, W, out, N_NODES);
    attn_kernel<<<N_INC / 4, 256, 0, stream>>>(out, node_idx, edge_idx, att, alpha, amax_u);
    expsum_kernel<<<(N_INC + 255) / 256, 256, 0, stream>>>(node_idx, edge_idx, alpha, amax_u, esum, Dn, Be);
    stage1_kernel<<<N_INC / 4, 256, 0, stream>>>(out, node_idx, edge_idx, alpha, esum, Be, edge_feat);
    hipMemsetAsync(d_out, 0, (size_t)N_NODES * DIM * sizeof(float), stream);
    stage2_kernel<<<N_INC / 4, 256, 0, stream>>>(edge_feat, node_idx, edge_idx, alpha, esum, Dn, out);
    stats_kernel<<<256, 256, 0, stream>>>(out, bias, stats);
    bn_kernel<<<(N_NODES * DIM + 255) / 256, 256, 0, stream>>>(out, bias, gamma, beta, stats);
}

// Round 3
// 476.978 us; speedup vs baseline: 4.8546x; 4.8546x over previous
//
#include <hip/hip_runtime.h>

#define N_NODES 50000
#define N_INC   300000
#define DIM     256
#define M_EDGES 20000
#define NEG_SLOPE 0.2f
#define BN_EPS  1e-5f

// ---------------- GEMM: C[M,256] = A[M,256] @ B[256,256], fp32 ----------------
#define BM 64
#define BN 64
#define BK 16
__global__ __launch_bounds__(256) void gemm_kernel(
    const float* __restrict__ A, const float* __restrict__ B,
    float* __restrict__ C, int Mrows)
{
    __shared__ float As[BK][BM + 4];
    __shared__ float Bs[BK][BN + 4];
    int tid = threadIdx.x;
    int tx = tid & 15, ty = tid >> 4;
    int bm = blockIdx.x * BM, bn = blockIdx.y * BN;
    float acc[4][4] = {};

    for (int k0 = 0; k0 < DIM; k0 += BK) {
        {
            int r = tid >> 2, kk = (tid & 3) * 4;
            int row = bm + r;
            float4 v = make_float4(0.f, 0.f, 0.f, 0.f);
            if (row < Mrows) v = *(const float4*)(A + (size_t)row * DIM + k0 + kk);
            As[kk + 0][r] = v.x; As[kk + 1][r] = v.y;
            As[kk + 2][r] = v.z; As[kk + 3][r] = v.w;
        }
        {
            int kr = tid >> 4, c4 = (tid & 15) * 4;
            float4 v = *(const float4*)(B + (size_t)(k0 + kr) * DIM + bn + c4);
            *(float4*)&Bs[kr][c4] = v;
        }
        __syncthreads();
        #pragma unroll
        for (int kk = 0; kk < BK; ++kk) {
            float4 a4 = *(const float4*)&As[kk][ty * 4];
            float4 b4 = *(const float4*)&Bs[kk][tx * 4];
            float a[4] = {a4.x, a4.y, a4.z, a4.w};
            float b[4] = {b4.x, b4.y, b4.z, b4.w};
            #pragma unroll
            for (int i = 0; i < 4; ++i)
                #pragma unroll
                for (int j = 0; j < 4; ++j)
                    acc[i][j] = fmaf(a[i], b[j], acc[i][j]);
        }
        __syncthreads();
    }
    #pragma unroll
    for (int i = 0; i < 4; ++i) {
        int row = bm + ty * 4 + i;
        if (row < Mrows) {
            float4 v = make_float4(acc[i][0], acc[i][1], acc[i][2], acc[i][3]);
            *(float4*)(C + (size_t)row * DIM + bn + tx * 4) = v;
        }
    }
}

// ------------- per-node attention dots: s1[n]=dot(xw[n],att[:256]), s2[n]=dot(xw[n],att[256:]) -------------
__global__ __launch_bounds__(256) void sdots_kernel(
    const float* __restrict__ xw, const float* __restrict__ att,
    float* __restrict__ s1, float* __restrict__ s2)
{
    int n = blockIdx.x * 4 + (threadIdx.x >> 6);
    if (n >= N_NODES) return;
    int lane = threadIdx.x & 63;
    float4 v  = *(const float4*)(xw + (size_t)n * DIM + lane * 4);
    float4 a1 = *(const float4*)(att + lane * 4);
    float4 a2 = *(const float4*)(att + DIM + lane * 4);
    float d1 = v.x * a1.x + v.y * a1.y + v.z * a1.z + v.w * a1.w;
    float d2 = v.x * a2.x + v.y * a2.y + v.z * a2.z + v.w * a2.w;
    #pragma unroll
    for (int off = 32; off >= 1; off >>= 1) {
        d1 += __shfl_down(d1, off);
        d2 += __shfl_down(d2, off);
    }
    if (lane == 0) { s1[n] = d1; s2[n] = d2; }
}

// ------------- alpha + degree histogram: one thread per incidence -------------
__global__ void alpha_kernel(
    const int* __restrict__ node_idx, const int* __restrict__ edge_idx,
    const float* __restrict__ s1, const float* __restrict__ s2,
    float* __restrict__ alpha, int* __restrict__ cnt_n, int* __restrict__ cnt_e)
{
    int e = blockIdx.x * blockDim.x + threadIdx.x;
    if (e >= N_INC) return;
    int n = node_idx[e], h = edge_idx[e];
    float a = s1[n] + s2[h];
    a = a > 0.f ? a : NEG_SLOPE * a;         // leaky_relu
    alpha[e] = a;
    atomicAdd(cnt_n + n, 1);
    atomicAdd(cnt_e + h, 1);
}

// ------------- single-block exclusive scan (per blockIdx: 0 -> edges, 1 -> nodes) -------------
__global__ __launch_bounds__(1024) void scan_kernel(
    const int* __restrict__ cnt_e, int* __restrict__ start_e,
    const int* __restrict__ cnt_n, int* __restrict__ start_n)
{
    const int* cnt = (blockIdx.x == 0) ? cnt_e : cnt_n;
    int* start     = (blockIdx.x == 0) ? start_e : start_n;
    int n          = (blockIdx.x == 0) ? M_EDGES : N_NODES;
    __shared__ int tile[1024];
    __shared__ int carry;
    int tid = threadIdx.x;
    if (tid == 0) carry = 0;
    __syncthreads();
    for (int base = 0; base < n; base += 1024) {
        int i = base + tid;
        int v = (i < n) ? cnt[i] : 0;
        tile[tid] = v;
        __syncthreads();
        #pragma unroll
        for (int off = 1; off < 1024; off <<= 1) {
            int t = (tid >= off) ? tile[tid - off] : 0;
            __syncthreads();
            tile[tid] += t;
            __syncthreads();
        }
        if (i < n) start[i + 1] = carry + tile[tid];   // inclusive -> start[i+1]
        int total = tile[1023];
        __syncthreads();
        if (tid == 0) carry += total;
        __syncthreads();
    }
    if (tid == 0) start[0] = 0;
}

// ------------- init cursors -------------
__global__ void initcur_kernel(const int* __restrict__ start_e, const int* __restrict__ start_n,
                               int* __restrict__ cur_e, int* __restrict__ cur_n)
{
    int i = blockIdx.x * blockDim.x + threadIdx.x;
    if (i < M_EDGES) cur_e[i] = start_e[i];
    if (i < N_NODES) cur_n[i] = start_n[i];
}

// ------------- CSR scatter: incidence id into both lists -------------
__global__ void scatter_kernel(
    const int* __restrict__ node_idx, const int* __restrict__ edge_idx,
    int* __restrict__ cur_e, int* __restrict__ cur_n,
    int* __restrict__ list_e, int* __restrict__ list_n)
{
    int e = blockIdx.x * blockDim.x + threadIdx.x;
    if (e >= N_INC) return;
    int p = atomicAdd(cur_e + edge_idx[e], 1);
    list_e[p] = e;
    int q = atomicAdd(cur_n + node_idx[e], 1);
    list_n[q] = e;
}

// ------------- per-node softmax stats: amax, 1/(esum+eps) -------------
__global__ void softstats_kernel(
    const float* __restrict__ alpha, const int* __restrict__ start_n,
    const int* __restrict__ list_n, float* __restrict__ amax, float* __restrict__ rnorm)
{
    int n = blockIdx.x * blockDim.x + threadIdx.x;
    if (n >= N_NODES) return;
    int j0 = start_n[n], j1 = start_n[n + 1];
    float m = -INFINITY;
    for (int j = j0; j < j1; ++j) m = fmaxf(m, alpha[list_n[j]]);
    if (j0 == j1) m = 0.f;                   // isfinite guard in reference
    float s = 0.f;
    for (int j = j0; j < j1; ++j) s += expf(alpha[list_n[j]] - m);
    amax[n] = m;
    rnorm[n] = 1.f / (s + 1e-16f);
}

// ------------- per-incidence weights: w1 = alpha_n*Binv, w2 = alpha_n*Dinv -------------
__global__ void weights_kernel(
    const int* __restrict__ node_idx, const int* __restrict__ edge_idx,
    const float* __restrict__ alpha, const float* __restrict__ amax,
    const float* __restrict__ rnorm, const int* __restrict__ start_e,
    const int* __restrict__ start_n, float* __restrict__ w1, float* __restrict__ w2)
{
    int e = blockIdx.x * blockDim.x + threadIdx.x;
    if (e >= N_INC) return;
    int n = node_idx[e], h = edge_idx[e];
    float an = expf(alpha[e] - amax[n]) * rnorm[n];
    float binv = 1.f / (float)(start_e[h + 1] - start_e[h]);
    float dinv = 1.f / (float)(start_n[n + 1] - start_n[n]);
    w1[e] = an * binv;
    w2[e] = an * dinv;
}

// ------------- stage 1: gather per hyperedge (wave per edge) -------------
__global__ __launch_bounds__(256) void stage1_kernel(
    const float* __restrict__ xw, const int* __restrict__ node_idx,
    const float* __restrict__ w1, const int* __restrict__ start_e,
    const int* __restrict__ list_e, float* __restrict__ edge_feat)
{
    int h = blockIdx.x * 4 + (threadIdx.x >> 6);
    if (h >= M_EDGES) return;
    int lane = threadIdx.x & 63;
    int j0 = start_e[h], j1 = start_e[h + 1];
    float4 acc = make_float4(0.f, 0.f, 0.f, 0.f);
    for (int j = j0; j < j1; ++j) {
        int e = list_e[j];
        float w = w1[e];
        int n = node_idx[e];
        float4 v = *(const float4*)(xw + (size_t)n * DIM + lane * 4);
        acc.x += w * v.x; acc.y += w * v.y; acc.z += w * v.z; acc.w += w * v.w;
    }
    *(float4*)(edge_feat + (size_t)h * DIM + lane * 4) = acc;
}

// ------------- stage 2: gather per node (wave per node), + bias -------------
__global__ __launch_bounds__(256) void stage2_kernel(
    const float* __restrict__ edge_feat, const int* __restrict__ edge_idx,
    const float* __restrict__ w2, const int* __restrict__ start_n,
    const int* __restrict__ list_n, const float* __restrict__ bias,
    float* __restrict__ out)
{
    int n = blockIdx.x * 4 + (threadIdx.x >> 6);
    if (n >= N_NODES) return;
    int lane = threadIdx.x & 63;
    int j0 = start_n[n], j1 = start_n[n + 1];
    float4 acc = make_float4(0.f, 0.f, 0.f, 0.f);
    for (int j = j0; j < j1; ++j) {
        int e = list_n[j];
        float w = w2[e];
        int h = edge_idx[e];
        float4 v = *(const float4*)(edge_feat + (size_t)h * DIM + lane * 4);
        acc.x += w * v.x; acc.y += w * v.y; acc.z += w * v.z; acc.w += w * v.w;
    }
    float4 b = *(const float4*)(bias + lane * 4);
    acc.x += b.x; acc.y += b.y; acc.z += b.z; acc.w += b.w;
    *(float4*)(out + (size_t)n * DIM + lane * 4) = acc;
}

// ------------- BN column stats -------------
__global__ __launch_bounds__(256) void stats_kernel(
    const float* __restrict__ out, float* __restrict__ stats)
{
    int c = threadIdx.x;
    int rows_per = (N_NODES + gridDim.x - 1) / gridDim.x;
    int r0 = blockIdx.x * rows_per;
    int r1 = min(r0 + rows_per, N_NODES);
    float sum = 0.f, sq = 0.f;
    for (int r = r0; r < r1; ++r) {
        float v = out[(size_t)r * DIM + c];
        sum += v; sq += v * v;
    }
    atomicAdd(stats + c, sum);
    atomicAdd(stats + DIM + c, sq);
}

// ------------- BN apply + ELU -------------
__global__ void bn_kernel(
    float* __restrict__ out, const float* __restrict__ gamma,
    const float* __restrict__ beta, const float* __restrict__ stats)
{
    int i = blockIdx.x * blockDim.x + threadIdx.x;
    if (i >= N_NODES * DIM) return;
    int c = i & (DIM - 1);
    float mu = stats[c] * (1.f / N_NODES);
    float var = stats[DIM + c] * (1.f / N_NODES) - mu * mu;
    float v = out[i];
    v = gamma[c] * (v - mu) * rsqrtf(var + BN_EPS) + beta[c];
    out[i] = v > 0.f ? v : expm1f(v);
}

extern "C" void kernel_launch(void* const* d_in, const int* in_sizes, int n_in,
                              void* d_out, int out_size, void* d_ws, size_t ws_size,
                              hipStream_t stream)
{
    const float* x        = (const float*)d_in[0];
    const int*   node_idx = (const int*)d_in[1];
    const int*   edge_idx = (const int*)d_in[2];
    const float* W        = (const float*)d_in[4];
    const float* att      = (const float*)d_in[5];
    const float* bias     = (const float*)d_in[6];
    const float* gamma    = (const float*)d_in[7];
    const float* beta     = (const float*)d_in[8];
    float* out = (float*)d_out;

    // workspace layout: edge_feat first (16B aligned), then zeroed region, then rest
    float* edge_feat = (float*)d_ws;                         // M*DIM
    int*   cnt_e   = (int*)(edge_feat + (size_t)M_EDGES * DIM); // M   (zeroed)
    int*   cnt_n   = cnt_e + M_EDGES;                        // N   (zeroed)
    float* stats   = (float*)(cnt_n + N_NODES);              // 2*DIM (zeroed)
    float* alpha   = stats + 2 * DIM;                        // E
    float* w1      = alpha + N_INC;                          // E
    float* w2      = w1 + N_INC;                             // E
    float* s1      = w2 + N_INC;                             // N
    float* s2      = s1 + N_NODES;                           // N
    float* amax    = s2 + N_NODES;                           // N
    float* rnorm   = amax + N_NODES;                         // N
    int*   start_e = (int*)(rnorm + N_NODES);                // M+1
    int*   start_n = start_e + M_EDGES + 1;                  // N+1
    int*   cur_e   = start_n + N_NODES + 1;                  // M
    int*   cur_n   = cur_e + M_EDGES;                        // N
    int*   list_e  = cur_n + N_NODES;                        // E
    int*   list_n  = list_e + N_INC;                         // E

    // zero only the histogram counters + stats
    hipMemsetAsync(cnt_e, 0, (size_t)(M_EDGES + N_NODES + 2 * DIM) * 4, stream);

    // xw lives in d_out until stage2 overwrites it
    gemm_kernel<<<dim3((N_NODES + BM - 1) / BM, DIM / BN), 256, 0, stream>>>(x, W, out, N_NODES);
    sdots_kernel<<<(N_NODES + 3) / 4, 256, 0, stream>>>(out, att, s1, s2);
    alpha_kernel<<<(N_INC + 255) / 256, 256, 0, stream>>>(node_idx, edge_idx, s1, s2, alpha, cnt_n, cnt_e);
    scan_kernel<<<2, 1024, 0, stream>>>(cnt_e, start_e, cnt_n, start_n);
    initcur_kernel<<<(N_NODES + 255) / 256, 256, 0, stream>>>(start_e, start_n, cur_e, cur_n);
    scatter_kernel<<<(N_INC + 255) / 256, 256, 0, stream>>>(node_idx, edge_idx, cur_e, cur_n, list_e, list_n);
    softstats_kernel<<<(N_NODES + 255) / 256, 256, 0, stream>>>(alpha, start_n, list_n, amax, rnorm);
    weights_kernel<<<(N_INC + 255) / 256, 256, 0, stream>>>(node_idx, edge_idx, alpha, amax, rnorm, start_e, start_n, w1, w2);
    stage1_kernel<<<(M_EDGES + 3) / 4, 256, 0, stream>>>(out, node_idx, w1, start_e, list_e, edge_feat);
    stage2_kernel<<<(N_NODES + 3) / 4, 256, 0, stream>>>(edge_feat, edge_idx, w2, start_n, list_n, bias, out);
    stats_kernel<<<256, 256, 0, stream>>>(out, stats);
    bn_kernel<<<(N_NODES * DIM + 255) / 256, 256, 0, stream>>>(out, gamma, beta, stats);
}

// Round 4
// 349.432 us; speedup vs baseline: 6.6266x; 1.3650x over previous
//
#include <hip/hip_runtime.h>

#define N_NODES 50000
#define N_INC   300000
#define DIM     256
#define M_EDGES 20000
#define NEG_SLOPE 0.2f
#define BN_EPS  1e-5f
#define EBLK 20
#define NBLK 49

typedef __attribute__((ext_vector_type(8))) short short8;
typedef __attribute__((ext_vector_type(4))) float f32x4;

__device__ __forceinline__ unsigned bf16rn(float f) {
    unsigned u = __float_as_uint(f);
    return (u + 0x7FFFu + ((u >> 16) & 1u)) >> 16;   // round-to-nearest-even
}

// ------------- W[k][n] f32 -> WT[n][k] bf16 -------------
__global__ void wt_kernel(const float* __restrict__ W, ushort* __restrict__ WT)
{
    int i = blockIdx.x * 256 + threadIdx.x;          // 65536
    int k = i >> 8, n = i & 255;
    WT[n * 256 + k] = (ushort)bf16rn(W[i]);
}

// ---------------- MFMA GEMM: C[50000,256] = A @ W, bf16 inputs, f32 acc ----------------
#define BMM 128
#define BNN 128
#define BKK 64
__global__ __launch_bounds__(256) void gemm_mfma(
    const float* __restrict__ A, const ushort* __restrict__ WT,
    float* __restrict__ C)
{
    __shared__ __align__(16) char lds[32768];
    char* As = lds;            // [128 rows][64 k] bf16, XOR-swizzled
    char* Bs = lds + 16384;    // [128 cols][64 k] bf16, XOR-swizzled
    int tid = threadIdx.x;
    int lane = tid & 63, w = tid >> 6;
    int wr = w >> 1, wc = w & 1;
    int bm = blockIdx.x * BMM, bn = blockIdx.y * BNN;
    f32x4 acc[4][4] = {};

    for (int k0 = 0; k0 < DIM; k0 += BKK) {
        __syncthreads();
        // stage A tile: 128 rows x 64 k, f32 -> bf16
        #pragma unroll
        for (int i = 0; i < 8; ++i) {
            int flat = tid + 256 * i;
            int row = flat >> 4, c4 = (flat & 15) * 4;
            float4 v = make_float4(0.f, 0.f, 0.f, 0.f);
            int gr = bm + row;
            if (gr < N_NODES) v = *(const float4*)(A + (size_t)gr * DIM + k0 + c4);
            uint2 p;
            p.x = bf16rn(v.x) | (bf16rn(v.y) << 16);
            p.y = bf16rn(v.z) | (bf16rn(v.w) << 16);
            int off = row * 128 + ((c4 * 2) ^ ((row & 7) << 4));
            *(uint2*)(As + off) = p;
        }
        // stage B tile from WT: 128 n x 64 k (already bf16)
        #pragma unroll
        for (int i = 0; i < 4; ++i) {
            int flat = tid + 256 * i;
            int n = flat >> 3, kc = (flat & 7) * 8;
            uint4 v = *(const uint4*)(WT + (size_t)(bn + n) * DIM + k0 + kc);
            int off = n * 128 + ((kc * 2) ^ ((n & 7) << 4));
            *(uint4*)(Bs + off) = v;
        }
        __syncthreads();
        #pragma unroll
        for (int kk = 0; kk < 2; ++kk) {
            short8 a[4], b[4];
            int kb = (kk * 32 + (lane >> 4) * 8) * 2;   // byte offset of 8-elem k-chunk
            #pragma unroll
            for (int m = 0; m < 4; ++m) {
                int row = wr * 64 + m * 16 + (lane & 15);
                a[m] = *(const short8*)(As + row * 128 + (kb ^ ((row & 7) << 4)));
            }
            #pragma unroll
            for (int nf = 0; nf < 4; ++nf) {
                int col = wc * 64 + nf * 16 + (lane & 15);
                b[nf] = *(const short8*)(Bs + col * 128 + (kb ^ ((col & 7) << 4)));
            }
            #pragma unroll
            for (int m = 0; m < 4; ++m)
                #pragma unroll
                for (int nf = 0; nf < 4; ++nf)
                    acc[m][nf] = __builtin_amdgcn_mfma_f32_16x16x32_bf16(
                        a[m], b[nf], acc[m][nf], 0, 0, 0);
        }
    }
    #pragma unroll
    for (int m = 0; m < 4; ++m)
        #pragma unroll
        for (int r = 0; r < 4; ++r) {
            int row = bm + wr * 64 + m * 16 + (lane >> 4) * 4 + r;
            if (row < N_NODES) {
                #pragma unroll
                for (int nf = 0; nf < 4; ++nf) {
                    int col = bn + wc * 64 + nf * 16 + (lane & 15);
                    C[(size_t)row * DIM + col] = acc[m][nf][r];
                }
            }
        }
}

// ------------- per-node attention dots -------------
__global__ __launch_bounds__(256) void sdots_kernel(
    const float* __restrict__ xw, const float* __restrict__ att,
    float* __restrict__ s1, float* __restrict__ s2)
{
    int n = blockIdx.x * 4 + (threadIdx.x >> 6);
    if (n >= N_NODES) return;
    int lane = threadIdx.x & 63;
    float4 v  = *(const float4*)(xw + (size_t)n * DIM + lane * 4);
    float4 a1 = *(const float4*)(att + lane * 4);
    float4 a2 = *(const float4*)(att + DIM + lane * 4);
    float d1 = v.x * a1.x + v.y * a1.y + v.z * a1.z + v.w * a1.w;
    float d2 = v.x * a2.x + v.y * a2.y + v.z * a2.z + v.w * a2.w;
    #pragma unroll
    for (int off = 32; off >= 1; off >>= 1) {
        d1 += __shfl_down(d1, off);
        d2 += __shfl_down(d2, off);
    }
    if (lane == 0) { s1[n] = d1; s2[n] = d2; }
}

// ------------- alpha + degree histogram -------------
__global__ void alpha_kernel(
    const int* __restrict__ node_idx, const int* __restrict__ edge_idx,
    const float* __restrict__ s1, const float* __restrict__ s2,
    float* __restrict__ alpha, int* __restrict__ cnt_n, int* __restrict__ cnt_e)
{
    int e = blockIdx.x * blockDim.x + threadIdx.x;
    if (e >= N_INC) return;
    int n = node_idx[e], h = edge_idx[e];
    float a = s1[n] + s2[h];
    a = a > 0.f ? a : NEG_SLOPE * a;
    alpha[e] = a;
    atomicAdd(cnt_n + n, 1);
    atomicAdd(cnt_e + h, 1);
}

// ------------- scan phase 1: per-block inclusive scan + block totals -------------
__global__ __launch_bounds__(1024) void scan_partial(
    const int* __restrict__ cnt_e, int* __restrict__ start_e, int* __restrict__ totals_e,
    const int* __restrict__ cnt_n, int* __restrict__ start_n, int* __restrict__ totals_n)
{
    int b = blockIdx.x;
    const int* cnt; int* start; int* totals; int n; int cb;
    if (b < EBLK) { cnt = cnt_e; start = start_e; totals = totals_e; n = M_EDGES; cb = b; }
    else          { cnt = cnt_n; start = start_n; totals = totals_n; n = N_NODES; cb = b - EBLK; }
    int tid = threadIdx.x, lane = tid & 63, wid = tid >> 6;
    int i = cb * 1024 + tid;
    int v = (i < n) ? cnt[i] : 0;
    #pragma unroll
    for (int off = 1; off < 64; off <<= 1) {
        int t = __shfl_up(v, off);
        if (lane >= off) v += t;
    }
    __shared__ int wsum[16];
    if (lane == 63) wsum[wid] = v;
    __syncthreads();
    if (wid == 0 && lane < 16) {
        int s = wsum[lane];
        #pragma unroll
        for (int off = 1; off < 16; off <<= 1) {
            int t = __shfl_up(s, off);
            if (lane >= off) s += t;
        }
        wsum[lane] = s;
    }
    __syncthreads();
    if (wid > 0) v += wsum[wid - 1];
    if (i < n) start[i + 1] = v;
    if (tid == 1023) totals[cb] = v;
}

// ------------- scan phase 2: scan block totals (1 block, 64 threads) -------------
__global__ void scan_totals(
    const int* __restrict__ totals_e, int* __restrict__ boff_e,
    const int* __restrict__ totals_n, int* __restrict__ boff_n,
    int* __restrict__ start_e, int* __restrict__ start_n)
{
    int lane = threadIdx.x;
    int ve0 = (lane < EBLK) ? totals_e[lane] : 0;
    int ve = ve0;
    #pragma unroll
    for (int off = 1; off < 64; off <<= 1) {
        int t = __shfl_up(ve, off);
        if (lane >= off) ve += t;
    }
    if (lane < EBLK) boff_e[lane] = ve - ve0;
    int vn0 = (lane < NBLK) ? totals_n[lane] : 0;
    int vn = vn0;
    #pragma unroll
    for (int off = 1; off < 64; off <<= 1) {
        int t = __shfl_up(vn, off);
        if (lane >= off) vn += t;
    }
    if (lane < NBLK) boff_n[lane] = vn - vn0;
    if (lane == 0) { start_e[0] = 0; start_n[0] = 0; }
}

// ------------- scan phase 3: add block offsets -------------
__global__ void scan_add(
    int* __restrict__ start_e, const int* __restrict__ boff_e,
    int* __restrict__ start_n, const int* __restrict__ boff_n)
{
    int id = blockIdx.x * 256 + threadIdx.x;
    if (id < M_EDGES) start_e[id + 1] += boff_e[id >> 10];
    else if (id < M_EDGES + N_NODES) {
        int j = id - M_EDGES;
        start_n[j + 1] += boff_n[j >> 10];
    }
}

// ------------- init cursors -------------
__global__ void initcur_kernel(const int* __restrict__ start_e, const int* __restrict__ start_n,
                               int* __restrict__ cur_e, int* __restrict__ cur_n)
{
    int i = blockIdx.x * blockDim.x + threadIdx.x;
    if (i < M_EDGES) cur_e[i] = start_e[i];
    if (i < N_NODES) cur_n[i] = start_n[i];
}

// ------------- CSR scatter -------------
__global__ void scatter_kernel(
    const int* __restrict__ node_idx, const int* __restrict__ edge_idx,
    int* __restrict__ cur_e, int* __restrict__ cur_n,
    int* __restrict__ list_e, int* __restrict__ list_n)
{
    int e = blockIdx.x * blockDim.x + threadIdx.x;
    if (e >= N_INC) return;
    int p = atomicAdd(cur_e + edge_idx[e], 1);
    list_e[p] = e;
    int q = atomicAdd(cur_n + node_idx[e], 1);
    list_n[q] = e;
}

// ------------- per-node softmax stats -------------
__global__ void softstats_kernel(
    const float* __restrict__ alpha, const int* __restrict__ start_n,
    const int* __restrict__ list_n, float* __restrict__ amax, float* __restrict__ rnorm)
{
    int n = blockIdx.x * blockDim.x + threadIdx.x;
    if (n >= N_NODES) return;
    int j0 = start_n[n], j1 = start_n[n + 1];
    float m = -INFINITY;
    for (int j = j0; j < j1; ++j) m = fmaxf(m, alpha[list_n[j]]);
    if (j0 == j1) m = 0.f;
    float s = 0.f;
    for (int j = j0; j < j1; ++j) s += expf(alpha[list_n[j]] - m);
    amax[n] = m;
    rnorm[n] = 1.f / (s + 1e-16f);
}

// ------------- per-incidence weights -------------
__global__ void weights_kernel(
    const int* __restrict__ node_idx, const int* __restrict__ edge_idx,
    const float* __restrict__ alpha, const float* __restrict__ amax,
    const float* __restrict__ rnorm, const int* __restrict__ start_e,
    const int* __restrict__ start_n, float* __restrict__ w1, float* __restrict__ w2)
{
    int e = blockIdx.x * blockDim.x + threadIdx.x;
    if (e >= N_INC) return;
    int n = node_idx[e], h = edge_idx[e];
    float an = expf(alpha[e] - amax[n]) * rnorm[n];
    float binv = 1.f / (float)(start_e[h + 1] - start_e[h]);
    float dinv = 1.f / (float)(start_n[n + 1] - start_n[n]);
    w1[e] = an * binv;
    w2[e] = an * dinv;
}

// ------------- stage 1: gather per hyperedge, shfl-broadcast metadata -------------
__global__ __launch_bounds__(256) void stage1_kernel(
    const float* __restrict__ xw, const int* __restrict__ node_idx,
    const float* __restrict__ w1, const int* __restrict__ start_e,
    const int* __restrict__ list_e, float* __restrict__ edge_feat)
{
    int h = blockIdx.x * 4 + (threadIdx.x >> 6);
    if (h >= M_EDGES) return;
    int lane = threadIdx.x & 63;
    int j0 = start_e[h], j1 = start_e[h + 1];
    float4 acc = make_float4(0.f, 0.f, 0.f, 0.f);
    for (int base = j0; base < j1; base += 64) {
        int cnt = min(64, j1 - base);
        float wv = 0.f; int nv = 0;
        if (lane < cnt) { int e = list_e[base + lane]; wv = w1[e]; nv = node_idx[e]; }
        for (int jj = 0; jj < cnt; ++jj) {
            float wgt = __shfl(wv, jj);
            int n = __shfl(nv, jj);
            float4 v = *(const float4*)(xw + (size_t)n * DIM + lane * 4);
            acc.x += wgt * v.x; acc.y += wgt * v.y;
            acc.z += wgt * v.z; acc.w += wgt * v.w;
        }
    }
    *(float4*)(edge_feat + (size_t)h * DIM + lane * 4) = acc;
}

// ------------- stage 2: gather per node, shfl-broadcast metadata, + bias -------------
__global__ __launch_bounds__(256) void stage2_kernel(
    const float* __restrict__ edge_feat, const int* __restrict__ edge_idx,
    const float* __restrict__ w2, const int* __restrict__ start_n,
    const int* __restrict__ list_n, const float* __restrict__ bias,
    float* __restrict__ out)
{
    int n = blockIdx.x * 4 + (threadIdx.x >> 6);
    if (n >= N_NODES) return;
    int lane = threadIdx.x & 63;
    int j0 = start_n[n], j1 = start_n[n + 1];
    float4 acc = make_float4(0.f, 0.f, 0.f, 0.f);
    for (int base = j0; base < j1; base += 64) {
        int cnt = min(64, j1 - base);
        float wv = 0.f; int hv = 0;
        if (lane < cnt) { int e = list_n[base + lane]; wv = w2[e]; hv = edge_idx[e]; }
        for (int jj = 0; jj < cnt; ++jj) {
            float wgt = __shfl(wv, jj);
            int h = __shfl(hv, jj);
            float4 v = *(const float4*)(edge_feat + (size_t)h * DIM + lane * 4);
            acc.x += wgt * v.x; acc.y += wgt * v.y;
            acc.z += wgt * v.z; acc.w += wgt * v.w;
        }
    }
    float4 b = *(const float4*)(bias + lane * 4);
    acc.x += b.x; acc.y += b.y; acc.z += b.z; acc.w += b.w;
    *(float4*)(out + (size_t)n * DIM + lane * 4) = acc;
}

// ------------- BN column stats -------------
__global__ __launch_bounds__(256) void stats_kernel(
    const float* __restrict__ out, float* __restrict__ stats)
{
    int c = threadIdx.x;
    int rows_per = (N_NODES + gridDim.x - 1) / gridDim.x;
    int r0 = blockIdx.x * rows_per;
    int r1 = min(r0 + rows_per, N_NODES);
    float sum = 0.f, sq = 0.f;
    for (int r = r0; r < r1; ++r) {
        float v = out[(size_t)r * DIM + c];
        sum += v; sq += v * v;
    }
    atomicAdd(stats + c, sum);
    atomicAdd(stats + DIM + c, sq);
}

// ------------- BN apply + ELU, float4 -------------
__global__ void bn_kernel(
    float* __restrict__ out, const float* __restrict__ gamma,
    const float* __restrict__ beta, const float* __restrict__ stats)
{
    int idx = blockIdx.x * blockDim.x + threadIdx.x;
    if (idx >= N_NODES * DIM / 4) return;
    int c = (idx & 63) * 4;
    float4 v = ((float4*)out)[idx];
    float* pv = &v.x;
    #pragma unroll
    for (int j = 0; j < 4; ++j) {
        float mu = stats[c + j] * (1.f / N_NODES);
        float var = stats[DIM + c + j] * (1.f / N_NODES) - mu * mu;
        float t = gamma[c + j] * (pv[j] - mu) * rsqrtf(var + BN_EPS) + beta[c + j];
        pv[j] = t > 0.f ? t : expm1f(t);
    }
    ((float4*)out)[idx] = v;
}

extern "C" void kernel_launch(void* const* d_in, const int* in_sizes, int n_in,
                              void* d_out, int out_size, void* d_ws, size_t ws_size,
                              hipStream_t stream)
{
    const float* x        = (const float*)d_in[0];
    const int*   node_idx = (const int*)d_in[1];
    const int*   edge_idx = (const int*)d_in[2];
    const float* W        = (const float*)d_in[4];
    const float* att      = (const float*)d_in[5];
    const float* bias     = (const float*)d_in[6];
    const float* gamma    = (const float*)d_in[7];
    const float* beta     = (const float*)d_in[8];
    float* out = (float*)d_out;

    float* edge_feat = (float*)d_ws;                            // M*DIM
    int*   cnt_e   = (int*)(edge_feat + (size_t)M_EDGES * DIM); // M   (zeroed)
    int*   cnt_n   = cnt_e + M_EDGES;                           // N   (zeroed)
    float* stats   = (float*)(cnt_n + N_NODES);                 // 2*DIM (zeroed)
    float* alpha   = stats + 2 * DIM;                           // E
    float* w1      = alpha + N_INC;                             // E
    float* w2      = w1 + N_INC;                                // E
    float* s1      = w2 + N_INC;                                // N
    float* s2      = s1 + N_NODES;                              // N
    float* amax    = s2 + N_NODES;                              // N
    float* rnorm   = amax + N_NODES;                            // N
    int*   start_e = (int*)(rnorm + N_NODES);                   // M+1
    int*   start_n = start_e + M_EDGES + 1;                     // N+1
    int*   cur_e   = start_n + N_NODES + 1;                     // M
    int*   cur_n   = cur_e + M_EDGES;                           // N
    int*   list_e  = cur_n + N_NODES;                           // E
    int*   list_n  = list_e + N_INC;                            // E
    ushort* WT     = (ushort*)(list_n + N_INC);                 // 256*256 bf16
    int*   totals_e = (int*)(WT + 256 * 256);                   // EBLK
    int*   boff_e   = totals_e + EBLK;                          // EBLK
    int*   totals_n = boff_e + EBLK;                            // NBLK
    int*   boff_n   = totals_n + NBLK;                          // NBLK

    hipMemsetAsync(cnt_e, 0, (size_t)(M_EDGES + N_NODES + 2 * DIM) * 4, stream);

    wt_kernel<<<256, 256, 0, stream>>>(W, WT);
    gemm_mfma<<<dim3((N_NODES + BMM - 1) / BMM, DIM / BNN), 256, 0, stream>>>(x, WT, out);
    sdots_kernel<<<(N_NODES + 3) / 4, 256, 0, stream>>>(out, att, s1, s2);
    alpha_kernel<<<(N_INC + 255) / 256, 256, 0, stream>>>(node_idx, edge_idx, s1, s2, alpha, cnt_n, cnt_e);
    scan_partial<<<EBLK + NBLK, 1024, 0, stream>>>(cnt_e, start_e, totals_e, cnt_n, start_n, totals_n);
    scan_totals<<<1, 64, 0, stream>>>(totals_e, boff_e, totals_n, boff_n, start_e, start_n);
    scan_add<<<(M_EDGES + N_NODES + 255) / 256, 256, 0, stream>>>(start_e, boff_e, start_n, boff_n);
    initcur_kernel<<<(N_NODES + 255) / 256, 256, 0, stream>>>(start_e, start_n, cur_e, cur_n);
    scatter_kernel<<<(N_INC + 255) / 256, 256, 0, stream>>>(node_idx, edge_idx, cur_e, cur_n, list_e, list_n);
    softstats_kernel<<<(N_NODES + 255) / 256, 256, 0, stream>>>(alpha, start_n, list_n, amax, rnorm);
    weights_kernel<<<(N_INC + 255) / 256, 256, 0, stream>>>(node_idx, edge_idx, alpha, amax, rnorm, start_e, start_n, w1, w2);
    stage1_kernel<<<(M_EDGES + 3) / 4, 256, 0, stream>>>(out, node_idx, w1, start_e, list_e, edge_feat);
    stage2_kernel<<<(N_NODES + 3) / 4, 256, 0, stream>>>(edge_feat, edge_idx, w2, start_n, list_n, bias, out);
    stats_kernel<<<256, 256, 0, stream>>>(out, stats);
    bn_kernel<<<(N_NODES * DIM / 4 + 255) / 256, 256, 0, stream>>>(out, gamma, beta, stats);
}

// Round 5
// 312.350 us; speedup vs baseline: 7.4133x; 1.1187x over previous
//
#include <hip/hip_runtime.h>

#define N_NODES 50000
#define N_INC   300000
#define DIM     256
#define M_EDGES 20000
#define NEG_SLOPE 0.2f
#define BN_EPS  1e-5f
#define EBLK 20
#define NBLK 49

typedef __attribute__((ext_vector_type(8))) short short8;
typedef __attribute__((ext_vector_type(4))) float f32x4;

__device__ __forceinline__ unsigned bf16rn(float f) {
    unsigned u = __float_as_uint(f);
    return (u + 0x7FFFu + ((u >> 16) & 1u)) >> 16;   // round-to-nearest-even
}
__device__ __forceinline__ float bf2f(unsigned us) {
    return __uint_as_float(us << 16);
}
// unpack 4 bf16 (uint2) -> float4
__device__ __forceinline__ float4 unp4(uint2 p) {
    return make_float4(__uint_as_float(p.x << 16),
                       __uint_as_float(p.x & 0xFFFF0000u),
                       __uint_as_float(p.y << 16),
                       __uint_as_float(p.y & 0xFFFF0000u));
}

// ------------- W[k][n] f32 -> WT[n][k] bf16 -------------
__global__ void wt_kernel(const float* __restrict__ W, ushort* __restrict__ WT)
{
    int i = blockIdx.x * 256 + threadIdx.x;          // 65536
    int k = i >> 8, n = i & 255;
    WT[n * 256 + k] = (ushort)bf16rn(W[i]);
}

// ---------------- MFMA GEMM: xwb[50000,256] (bf16) = A @ W ----------------
#define BMM 128
#define BNN 128
#define BKK 64
__global__ __launch_bounds__(256) void gemm_mfma(
    const float* __restrict__ A, const ushort* __restrict__ WT,
    ushort* __restrict__ xwb)
{
    __shared__ __align__(16) char lds[32768];
    char* As = lds;            // [128 rows][64 k] bf16, XOR-swizzled
    char* Bs = lds + 16384;    // [128 cols][64 k] bf16, XOR-swizzled
    int tid = threadIdx.x;
    int lane = tid & 63, w = tid >> 6;
    int wr = w >> 1, wc = w & 1;
    int bm = blockIdx.x * BMM, bn = blockIdx.y * BNN;
    f32x4 acc[4][4] = {};

    for (int k0 = 0; k0 < DIM; k0 += BKK) {
        __syncthreads();
        #pragma unroll
        for (int i = 0; i < 8; ++i) {
            int flat = tid + 256 * i;
            int row = flat >> 4, c4 = (flat & 15) * 4;
            float4 v = make_float4(0.f, 0.f, 0.f, 0.f);
            int gr = bm + row;
            if (gr < N_NODES) v = *(const float4*)(A + (size_t)gr * DIM + k0 + c4);
            uint2 p;
            p.x = bf16rn(v.x) | (bf16rn(v.y) << 16);
            p.y = bf16rn(v.z) | (bf16rn(v.w) << 16);
            int off = row * 128 + ((c4 * 2) ^ ((row & 7) << 4));
            *(uint2*)(As + off) = p;
        }
        #pragma unroll
        for (int i = 0; i < 4; ++i) {
            int flat = tid + 256 * i;
            int n = flat >> 3, kc = (flat & 7) * 8;
            uint4 v = *(const uint4*)(WT + (size_t)(bn + n) * DIM + k0 + kc);
            int off = n * 128 + ((kc * 2) ^ ((n & 7) << 4));
            *(uint4*)(Bs + off) = v;
        }
        __syncthreads();
        #pragma unroll
        for (int kk = 0; kk < 2; ++kk) {
            short8 a[4], b[4];
            int kb = (kk * 32 + (lane >> 4) * 8) * 2;
            #pragma unroll
            for (int m = 0; m < 4; ++m) {
                int row = wr * 64 + m * 16 + (lane & 15);
                a[m] = *(const short8*)(As + row * 128 + (kb ^ ((row & 7) << 4)));
            }
            #pragma unroll
            for (int nf = 0; nf < 4; ++nf) {
                int col = wc * 64 + nf * 16 + (lane & 15);
                b[nf] = *(const short8*)(Bs + col * 128 + (kb ^ ((col & 7) << 4)));
            }
            #pragma unroll
            for (int m = 0; m < 4; ++m)
                #pragma unroll
                for (int nf = 0; nf < 4; ++nf)
                    acc[m][nf] = __builtin_amdgcn_mfma_f32_16x16x32_bf16(
                        a[m], b[nf], acc[m][nf], 0, 0, 0);
        }
    }
    // epilogue: f32 acc -> bf16 stores
    #pragma unroll
    for (int m = 0; m < 4; ++m)
        #pragma unroll
        for (int r = 0; r < 4; ++r) {
            int row = bm + wr * 64 + m * 16 + (lane >> 4) * 4 + r;
            if (row < N_NODES) {
                #pragma unroll
                for (int nf = 0; nf < 4; ++nf) {
                    int col = bn + wc * 64 + nf * 16 + (lane & 15);
                    xwb[(size_t)row * DIM + col] = (ushort)bf16rn(acc[m][nf][r]);
                }
            }
        }
}

// ------------- per-node attention dots (bf16 xw) -------------
__global__ __launch_bounds__(256) void sdots_kernel(
    const ushort* __restrict__ xwb, const float* __restrict__ att,
    float* __restrict__ s1, float* __restrict__ s2)
{
    int n = blockIdx.x * 4 + (threadIdx.x >> 6);
    if (n >= N_NODES) return;
    int lane = threadIdx.x & 63;
    float4 v  = unp4(*(const uint2*)(xwb + (size_t)n * DIM + lane * 4));
    float4 a1 = *(const float4*)(att + lane * 4);
    float4 a2 = *(const float4*)(att + DIM + lane * 4);
    float d1 = v.x * a1.x + v.y * a1.y + v.z * a1.z + v.w * a1.w;
    float d2 = v.x * a2.x + v.y * a2.y + v.z * a2.z + v.w * a2.w;
    #pragma unroll
    for (int off = 32; off >= 1; off >>= 1) {
        d1 += __shfl_down(d1, off);
        d2 += __shfl_down(d2, off);
    }
    if (lane == 0) { s1[n] = d1; s2[n] = d2; }
}

// ------------- alpha + degree histogram -------------
__global__ void alpha_kernel(
    const int* __restrict__ node_idx, const int* __restrict__ edge_idx,
    const float* __restrict__ s1, const float* __restrict__ s2,
    float* __restrict__ alpha, int* __restrict__ cnt_n, int* __restrict__ cnt_e)
{
    int e = blockIdx.x * blockDim.x + threadIdx.x;
    if (e >= N_INC) return;
    int n = node_idx[e], h = edge_idx[e];
    float a = s1[n] + s2[h];
    a = a > 0.f ? a : NEG_SLOPE * a;
    alpha[e] = a;
    atomicAdd(cnt_n + n, 1);
    atomicAdd(cnt_e + h, 1);
}

// ------------- scan phase 1 -------------
__global__ __launch_bounds__(1024) void scan_partial(
    const int* __restrict__ cnt_e, int* __restrict__ start_e, int* __restrict__ totals_e,
    const int* __restrict__ cnt_n, int* __restrict__ start_n, int* __restrict__ totals_n)
{
    int b = blockIdx.x;
    const int* cnt; int* start; int* totals; int n; int cb;
    if (b < EBLK) { cnt = cnt_e; start = start_e; totals = totals_e; n = M_EDGES; cb = b; }
    else          { cnt = cnt_n; start = start_n; totals = totals_n; n = N_NODES; cb = b - EBLK; }
    int tid = threadIdx.x, lane = tid & 63, wid = tid >> 6;
    int i = cb * 1024 + tid;
    int v = (i < n) ? cnt[i] : 0;
    #pragma unroll
    for (int off = 1; off < 64; off <<= 1) {
        int t = __shfl_up(v, off);
        if (lane >= off) v += t;
    }
    __shared__ int wsum[16];
    if (lane == 63) wsum[wid] = v;
    __syncthreads();
    if (wid == 0 && lane < 16) {
        int s = wsum[lane];
        #pragma unroll
        for (int off = 1; off < 16; off <<= 1) {
            int t = __shfl_up(s, off);
            if (lane >= off) s += t;
        }
        wsum[lane] = s;
    }
    __syncthreads();
    if (wid > 0) v += wsum[wid - 1];
    if (i < n) start[i + 1] = v;
    if (tid == 1023) totals[cb] = v;
}

// ------------- scan phase 2 -------------
__global__ void scan_totals(
    const int* __restrict__ totals_e, int* __restrict__ boff_e,
    const int* __restrict__ totals_n, int* __restrict__ boff_n,
    int* __restrict__ start_e, int* __restrict__ start_n)
{
    int lane = threadIdx.x;
    int ve0 = (lane < EBLK) ? totals_e[lane] : 0;
    int ve = ve0;
    #pragma unroll
    for (int off = 1; off < 64; off <<= 1) {
        int t = __shfl_up(ve, off);
        if (lane >= off) ve += t;
    }
    if (lane < EBLK) boff_e[lane] = ve - ve0;
    int vn0 = (lane < NBLK) ? totals_n[lane] : 0;
    int vn = vn0;
    #pragma unroll
    for (int off = 1; off < 64; off <<= 1) {
        int t = __shfl_up(vn, off);
        if (lane >= off) vn += t;
    }
    if (lane < NBLK) boff_n[lane] = vn - vn0;
    if (lane == 0) { start_e[0] = 0; start_n[0] = 0; }
}

// ------------- scan phase 3 -------------
__global__ void scan_add(
    int* __restrict__ start_e, const int* __restrict__ boff_e,
    int* __restrict__ start_n, const int* __restrict__ boff_n)
{
    int id = blockIdx.x * 256 + threadIdx.x;
    if (id < M_EDGES) start_e[id + 1] += boff_e[id >> 10];
    else if (id < M_EDGES + N_NODES) {
        int j = id - M_EDGES;
        start_n[j + 1] += boff_n[j >> 10];
    }
}

// ------------- init cursors -------------
__global__ void initcur_kernel(const int* __restrict__ start_e, const int* __restrict__ start_n,
                               int* __restrict__ cur_e, int* __restrict__ cur_n)
{
    int i = blockIdx.x * blockDim.x + threadIdx.x;
    if (i < M_EDGES) cur_e[i] = start_e[i];
    if (i < N_NODES) cur_n[i] = start_n[i];
}

// ------------- CSR scatter -------------
__global__ void scatter_kernel(
    const int* __restrict__ node_idx, const int* __restrict__ edge_idx,
    int* __restrict__ cur_e, int* __restrict__ cur_n,
    int* __restrict__ list_e, int* __restrict__ list_n)
{
    int e = blockIdx.x * blockDim.x + threadIdx.x;
    if (e >= N_INC) return;
    int p = atomicAdd(cur_e + edge_idx[e], 1);
    list_e[p] = e;
    int q = atomicAdd(cur_n + node_idx[e], 1);
    list_n[q] = e;
}

// ------------- per-node softmax stats -------------
__global__ void softstats_kernel(
    const float* __restrict__ alpha, const int* __restrict__ start_n,
    const int* __restrict__ list_n, float* __restrict__ amax, float* __restrict__ rnorm)
{
    int n = blockIdx.x * blockDim.x + threadIdx.x;
    if (n >= N_NODES) return;
    int j0 = start_n[n], j1 = start_n[n + 1];
    float m = -INFINITY;
    for (int j = j0; j < j1; ++j) m = fmaxf(m, alpha[list_n[j]]);
    if (j0 == j1) m = 0.f;
    float s = 0.f;
    for (int j = j0; j < j1; ++j) s += expf(alpha[list_n[j]] - m);
    amax[n] = m;
    rnorm[n] = 1.f / (s + 1e-16f);
}

// ------------- per-incidence weights -------------
__global__ void weights_kernel(
    const int* __restrict__ node_idx, const int* __restrict__ edge_idx,
    const float* __restrict__ alpha, const float* __restrict__ amax,
    const float* __restrict__ rnorm, const int* __restrict__ start_e,
    const int* __restrict__ start_n, float* __restrict__ w1, float* __restrict__ w2)
{
    int e = blockIdx.x * blockDim.x + threadIdx.x;
    if (e >= N_INC) return;
    int n = node_idx[e], h = edge_idx[e];
    float an = expf(alpha[e] - amax[n]) * rnorm[n];
    float binv = 1.f / (float)(start_e[h + 1] - start_e[h]);
    float dinv = 1.f / (float)(start_n[n + 1] - start_n[n]);
    w1[e] = an * binv;
    w2[e] = an * dinv;
}

// ------------- stage 1: gather bf16 xw per hyperedge -> bf16 edge_feat -------------
__global__ __launch_bounds__(256) void stage1_kernel(
    const ushort* __restrict__ xwb, const int* __restrict__ node_idx,
    const float* __restrict__ w1, const int* __restrict__ start_e,
    const int* __restrict__ list_e, ushort* __restrict__ edge_feat)
{
    int h = blockIdx.x * 4 + (threadIdx.x >> 6);
    if (h >= M_EDGES) return;
    int lane = threadIdx.x & 63;
    int j0 = start_e[h], j1 = start_e[h + 1];
    float4 acc = make_float4(0.f, 0.f, 0.f, 0.f);
    for (int base = j0; base < j1; base += 64) {
        int cnt = min(64, j1 - base);
        float wv = 0.f; int nv = 0;
        if (lane < cnt) { int e = list_e[base + lane]; wv = w1[e]; nv = node_idx[e]; }
        int jj = 0;
        for (; jj + 2 <= cnt; jj += 2) {
            float wg0 = __shfl(wv, jj);     int n0 = __shfl(nv, jj);
            float wg1 = __shfl(wv, jj + 1); int n1 = __shfl(nv, jj + 1);
            uint2 p0 = *(const uint2*)(xwb + (size_t)n0 * DIM + lane * 4);
            uint2 p1 = *(const uint2*)(xwb + (size_t)n1 * DIM + lane * 4);
            float4 v0 = unp4(p0), v1 = unp4(p1);
            acc.x += wg0 * v0.x + wg1 * v1.x;
            acc.y += wg0 * v0.y + wg1 * v1.y;
            acc.z += wg0 * v0.z + wg1 * v1.z;
            acc.w += wg0 * v0.w + wg1 * v1.w;
        }
        if (jj < cnt) {
            float wg = __shfl(wv, jj); int n0 = __shfl(nv, jj);
            float4 v = unp4(*(const uint2*)(xwb + (size_t)n0 * DIM + lane * 4));
            acc.x += wg * v.x; acc.y += wg * v.y;
            acc.z += wg * v.z; acc.w += wg * v.w;
        }
    }
    uint2 p;
    p.x = bf16rn(acc.x) | (bf16rn(acc.y) << 16);
    p.y = bf16rn(acc.z) | (bf16rn(acc.w) << 16);
    *(uint2*)(edge_feat + (size_t)h * DIM + lane * 4) = p;
}

// ------------- stage 2: gather bf16 edge_feat per node, + bias -> f32 out -------------
__global__ __launch_bounds__(256) void stage2_kernel(
    const ushort* __restrict__ edge_feat, const int* __restrict__ edge_idx,
    const float* __restrict__ w2, const int* __restrict__ start_n,
    const int* __restrict__ list_n, const float* __restrict__ bias,
    float* __restrict__ out)
{
    int n = blockIdx.x * 4 + (threadIdx.x >> 6);
    if (n >= N_NODES) return;
    int lane = threadIdx.x & 63;
    int j0 = start_n[n], j1 = start_n[n + 1];
    float4 acc = make_float4(0.f, 0.f, 0.f, 0.f);
    for (int base = j0; base < j1; base += 64) {
        int cnt = min(64, j1 - base);
        float wv = 0.f; int hv = 0;
        if (lane < cnt) { int e = list_n[base + lane]; wv = w2[e]; hv = edge_idx[e]; }
        int jj = 0;
        for (; jj + 2 <= cnt; jj += 2) {
            float wg0 = __shfl(wv, jj);     int h0 = __shfl(hv, jj);
            float wg1 = __shfl(wv, jj + 1); int h1 = __shfl(hv, jj + 1);
            uint2 p0 = *(const uint2*)(edge_feat + (size_t)h0 * DIM + lane * 4);
            uint2 p1 = *(const uint2*)(edge_feat + (size_t)h1 * DIM + lane * 4);
            float4 v0 = unp4(p0), v1 = unp4(p1);
            acc.x += wg0 * v0.x + wg1 * v1.x;
            acc.y += wg0 * v0.y + wg1 * v1.y;
            acc.z += wg0 * v0.z + wg1 * v1.z;
            acc.w += wg0 * v0.w + wg1 * v1.w;
        }
        if (jj < cnt) {
            float wg = __shfl(wv, jj); int h0 = __shfl(hv, jj);
            float4 v = unp4(*(const uint2*)(edge_feat + (size_t)h0 * DIM + lane * 4));
            acc.x += wg * v.x; acc.y += wg * v.y;
            acc.z += wg * v.z; acc.w += wg * v.w;
        }
    }
    float4 b = *(const float4*)(bias + lane * 4);
    acc.x += b.x; acc.y += b.y; acc.z += b.z; acc.w += b.w;
    *(float4*)(out + (size_t)n * DIM + lane * 4) = acc;
}

// ------------- BN column stats -------------
__global__ __launch_bounds__(256) void stats_kernel(
    const float* __restrict__ out, float* __restrict__ stats)
{
    int c = threadIdx.x;
    int rows_per = (N_NODES + gridDim.x - 1) / gridDim.x;
    int r0 = blockIdx.x * rows_per;
    int r1 = min(r0 + rows_per, N_NODES);
    float sum = 0.f, sq = 0.f;
    for (int r = r0; r < r1; ++r) {
        float v = out[(size_t)r * DIM + c];
        sum += v; sq += v * v;
    }
    atomicAdd(stats + c, sum);
    atomicAdd(stats + DIM + c, sq);
}

// ------------- BN apply + ELU, float4 -------------
__global__ void bn_kernel(
    float* __restrict__ out, const float* __restrict__ gamma,
    const float* __restrict__ beta, const float* __restrict__ stats)
{
    int idx = blockIdx.x * blockDim.x + threadIdx.x;
    if (idx >= N_NODES * DIM / 4) return;
    int c = (idx & 63) * 4;
    float4 v = ((float4*)out)[idx];
    float* pv = &v.x;
    #pragma unroll
    for (int j = 0; j < 4; ++j) {
        float mu = stats[c + j] * (1.f / N_NODES);
        float var = stats[DIM + c + j] * (1.f / N_NODES) - mu * mu;
        float t = gamma[c + j] * (pv[j] - mu) * rsqrtf(var + BN_EPS) + beta[c + j];
        pv[j] = t > 0.f ? t : expm1f(t);
    }
    ((float4*)out)[idx] = v;
}

extern "C" void kernel_launch(void* const* d_in, const int* in_sizes, int n_in,
                              void* d_out, int out_size, void* d_ws, size_t ws_size,
                              hipStream_t stream)
{
    const float* x        = (const float*)d_in[0];
    const int*   node_idx = (const int*)d_in[1];
    const int*   edge_idx = (const int*)d_in[2];
    const float* W        = (const float*)d_in[4];
    const float* att      = (const float*)d_in[5];
    const float* bias     = (const float*)d_in[6];
    const float* gamma    = (const float*)d_in[7];
    const float* beta     = (const float*)d_in[8];
    float* out = (float*)d_out;
    ushort* xwb = (ushort*)d_out;     // bf16 xw occupies first 26 MB of d_out; overwritten by stage2

    ushort* edge_feat = (ushort*)d_ws;                          // M*DIM bf16
    int*   cnt_e   = (int*)(edge_feat + (size_t)M_EDGES * DIM); // M   (zeroed)
    int*   cnt_n   = cnt_e + M_EDGES;                           // N   (zeroed)
    float* stats   = (float*)(cnt_n + N_NODES);                 // 2*DIM (zeroed)
    float* alpha   = stats + 2 * DIM;                           // E
    float* w1      = alpha + N_INC;                             // E
    float* w2      = w1 + N_INC;                                // E
    float* s1      = w2 + N_INC;                                // N
    float* s2      = s1 + N_NODES;                              // N
    float* amax    = s2 + N_NODES;                              // N
    float* rnorm   = amax + N_NODES;                            // N
    int*   start_e = (int*)(rnorm + N_NODES);                   // M+1
    int*   start_n = start_e + M_EDGES + 1;                     // N+1
    int*   cur_e   = start_n + N_NODES + 1;                     // M
    int*   cur_n   = cur_e + M_EDGES;                           // N
    int*   list_e  = cur_n + N_NODES;                           // E
    int*   list_n  = list_e + N_INC;                            // E
    ushort* WT     = (ushort*)(list_n + N_INC);                 // 256*256 bf16
    int*   totals_e = (int*)(WT + 256 * 256);                   // EBLK
    int*   boff_e   = totals_e + EBLK;                          // EBLK
    int*   totals_n = boff_e + EBLK;                            // NBLK
    int*   boff_n   = totals_n + NBLK;                          // NBLK

    hipMemsetAsync(cnt_e, 0, (size_t)(M_EDGES + N_NODES + 2 * DIM) * 4, stream);

    wt_kernel<<<256, 256, 0, stream>>>(W, WT);
    gemm_mfma<<<dim3((N_NODES + BMM - 1) / BMM, DIM / BNN), 256, 0, stream>>>(x, WT, xwb);
    sdots_kernel<<<(N_NODES + 3) / 4, 256, 0, stream>>>(xwb, att, s1, s2);
    alpha_kernel<<<(N_INC + 255) / 256, 256, 0, stream>>>(node_idx, edge_idx, s1, s2, alpha, cnt_n, cnt_e);
    scan_partial<<<EBLK + NBLK, 1024, 0, stream>>>(cnt_e, start_e, totals_e, cnt_n, start_n, totals_n);
    scan_totals<<<1, 64, 0, stream>>>(totals_e, boff_e, totals_n, boff_n, start_e, start_n);
    scan_add<<<(M_EDGES + N_NODES + 255) / 256, 256, 0, stream>>>(start_e, boff_e, start_n, boff_n);
    initcur_kernel<<<(N_NODES + 255) / 256, 256, 0, stream>>>(start_e, start_n, cur_e, cur_n);
    scatter_kernel<<<(N_INC + 255) / 256, 256, 0, stream>>>(node_idx, edge_idx, cur_e, cur_n, list_e, list_n);
    softstats_kernel<<<(N_NODES + 255) / 256, 256, 0, stream>>>(alpha, start_n, list_n, amax, rnorm);
    weights_kernel<<<(N_INC + 255) / 256, 256, 0, stream>>>(node_idx, edge_idx, alpha, amax, rnorm, start_e, start_n, w1, w2);
    stage1_kernel<<<(M_EDGES + 3) / 4, 256, 0, stream>>>(xwb, node_idx, w1, start_e, list_e, edge_feat);
    stage2_kernel<<<(N_NODES + 3) / 4, 256, 0, stream>>>(edge_feat, edge_idx, w2, start_n, list_n, bias, out);
    stats_kernel<<<256, 256, 0, stream>>>(out, stats);
    bn_kernel<<<(N_NODES * DIM / 4 + 255) / 256, 256, 0, stream>>>(out, gamma, beta, stats);
}

// Round 6
// 254.525 us; speedup vs baseline: 9.0975x; 1.2272x over previous
//
#include <hip/hip_runtime.h>

#define N_NODES 50000
#define N_INC   300000
#define DIM     256
#define M_EDGES 20000
#define NEG_SLOPE 0.2f
#define BN_EPS  1e-5f
#define EBLK 20
#define NBLK 49

typedef __attribute__((ext_vector_type(8))) short short8;
typedef __attribute__((ext_vector_type(4))) float f32x4;

__device__ __forceinline__ unsigned bf16rn(float f) {
    unsigned u = __float_as_uint(f);
    return (u + 0x7FFFu + ((u >> 16) & 1u)) >> 16;   // round-to-nearest-even
}
// unpack 4 bf16 (uint2) -> float4
__device__ __forceinline__ float4 unp4(uint2 p) {
    return make_float4(__uint_as_float(p.x << 16),
                       __uint_as_float(p.x & 0xFFFF0000u),
                       __uint_as_float(p.y << 16),
                       __uint_as_float(p.y & 0xFFFF0000u));
}

// ------------- W[k][n] f32 -> WT[n][k] bf16 -------------
__global__ void wt_kernel(const float* __restrict__ W, ushort* __restrict__ WT)
{
    int i = blockIdx.x * 256 + threadIdx.x;          // 65536
    int k = i >> 8, n = i & 255;
    WT[n * 256 + k] = (ushort)bf16rn(W[i]);
}

// ---------------- MFMA GEMM: xwb (bf16) = A @ W ; fused s1/s2 attention dots ----------------
#define BMM 128
#define BNN 128
#define BKK 64
__global__ __launch_bounds__(256) void gemm_mfma(
    const float* __restrict__ A, const ushort* __restrict__ WT,
    const float* __restrict__ att,
    ushort* __restrict__ xwb, float* __restrict__ s1, float* __restrict__ s2)
{
    __shared__ __align__(16) char lds[32768];
    char* As = lds;            // [128 rows][64 k] bf16, XOR-swizzled
    char* Bs = lds + 16384;    // [128 cols][64 k] bf16, XOR-swizzled
    int tid = threadIdx.x;
    int lane = tid & 63, w = tid >> 6;
    int wr = w >> 1, wc = w & 1;
    int bm = blockIdx.x * BMM, bn = blockIdx.y * BNN;
    f32x4 acc[4][4] = {};

    for (int k0 = 0; k0 < DIM; k0 += BKK) {
        __syncthreads();
        #pragma unroll
        for (int i = 0; i < 8; ++i) {
            int flat = tid + 256 * i;
            int row = flat >> 4, c4 = (flat & 15) * 4;
            float4 v = make_float4(0.f, 0.f, 0.f, 0.f);
            int gr = bm + row;
            if (gr < N_NODES) v = *(const float4*)(A + (size_t)gr * DIM + k0 + c4);
            uint2 p;
            p.x = bf16rn(v.x) | (bf16rn(v.y) << 16);
            p.y = bf16rn(v.z) | (bf16rn(v.w) << 16);
            int off = row * 128 + ((c4 * 2) ^ ((row & 7) << 4));
            *(uint2*)(As + off) = p;
        }
        #pragma unroll
        for (int i = 0; i < 4; ++i) {
            int flat = tid + 256 * i;
            int n = flat >> 3, kc = (flat & 7) * 8;
            uint4 v = *(const uint4*)(WT + (size_t)(bn + n) * DIM + k0 + kc);
            int off = n * 128 + ((kc * 2) ^ ((n & 7) << 4));
            *(uint4*)(Bs + off) = v;
        }
        __syncthreads();
        #pragma unroll
        for (int kk = 0; kk < 2; ++kk) {
            short8 a[4], b[4];
            int kb = (kk * 32 + (lane >> 4) * 8) * 2;
            #pragma unroll
            for (int m = 0; m < 4; ++m) {
                int row = wr * 64 + m * 16 + (lane & 15);
                a[m] = *(const short8*)(As + row * 128 + (kb ^ ((row & 7) << 4)));
            }
            #pragma unroll
            for (int nf = 0; nf < 4; ++nf) {
                int col = wc * 64 + nf * 16 + (lane & 15);
                b[nf] = *(const short8*)(Bs + col * 128 + (kb ^ ((col & 7) << 4)));
            }
            #pragma unroll
            for (int m = 0; m < 4; ++m)
                #pragma unroll
                for (int nf = 0; nf < 4; ++nf)
                    acc[m][nf] = __builtin_amdgcn_mfma_f32_16x16x32_bf16(
                        a[m], b[nf], acc[m][nf], 0, 0, 0);
        }
    }
    // att columns this thread touches (4 cols per nf group)
    float att1v[4], att2v[4];
    #pragma unroll
    for (int nf = 0; nf < 4; ++nf) {
        int col = bn + wc * 64 + nf * 16 + (lane & 15);
        att1v[nf] = att[col];
        att2v[nf] = att[DIM + col];
    }
    #pragma unroll
    for (int m = 0; m < 4; ++m)
        #pragma unroll
        for (int r = 0; r < 4; ++r) {
            int row = bm + wr * 64 + m * 16 + (lane >> 4) * 4 + r;
            // bf16 store of xw
            if (row < N_NODES) {
                #pragma unroll
                for (int nf = 0; nf < 4; ++nf) {
                    int col = bn + wc * 64 + nf * 16 + (lane & 15);
                    xwb[(size_t)row * DIM + col] = (ushort)bf16rn(acc[m][nf][r]);
                }
            }
            // fused partial attention dots (from f32 acc)
            float p1 = 0.f, p2 = 0.f;
            #pragma unroll
            for (int nf = 0; nf < 4; ++nf) {
                float v = acc[m][nf][r];
                p1 += v * att1v[nf];
                p2 += v * att2v[nf];
            }
            #pragma unroll
            for (int msk = 1; msk < 16; msk <<= 1) {
                p1 += __shfl_xor(p1, msk);
                p2 += __shfl_xor(p2, msk);
            }
            if ((lane & 15) == 0 && row < N_NODES) {
                atomicAdd(s1 + row, p1);
                atomicAdd(s2 + row, p2);
            }
        }
}

// ------------- alpha: leaky + exp, esum + degree histograms -------------
__global__ void alpha_kernel(
    const int* __restrict__ node_idx, const int* __restrict__ edge_idx,
    const float* __restrict__ s1, const float* __restrict__ s2,
    float* __restrict__ ealpha, float* __restrict__ esum,
    int* __restrict__ cnt_n, int* __restrict__ cnt_e)
{
    int e = blockIdx.x * blockDim.x + threadIdx.x;
    if (e >= N_INC) return;
    int n = node_idx[e], h = edge_idx[e];
    float a = s1[n] + s2[h];
    a = a > 0.f ? a : NEG_SLOPE * a;
    float ea = __expf(a);                 // no max-subtraction: |a| <~ 12, safe in f32
    ealpha[e] = ea;
    atomicAdd(esum + n, ea);
    atomicAdd(cnt_n + n, 1);
    atomicAdd(cnt_e + h, 1);
}

// ------------- scan phase 1 -------------
__global__ __launch_bounds__(1024) void scan_partial(
    const int* __restrict__ cnt_e, int* __restrict__ start_e, int* __restrict__ totals_e,
    const int* __restrict__ cnt_n, int* __restrict__ start_n, int* __restrict__ totals_n)
{
    int b = blockIdx.x;
    const int* cnt; int* start; int* totals; int n; int cb;
    if (b < EBLK) { cnt = cnt_e; start = start_e; totals = totals_e; n = M_EDGES; cb = b; }
    else          { cnt = cnt_n; start = start_n; totals = totals_n; n = N_NODES; cb = b - EBLK; }
    int tid = threadIdx.x, lane = tid & 63, wid = tid >> 6;
    int i = cb * 1024 + tid;
    int v = (i < n) ? cnt[i] : 0;
    #pragma unroll
    for (int off = 1; off < 64; off <<= 1) {
        int t = __shfl_up(v, off);
        if (lane >= off) v += t;
    }
    __shared__ int wsum[16];
    if (lane == 63) wsum[wid] = v;
    __syncthreads();
    if (wid == 0 && lane < 16) {
        int s = wsum[lane];
        #pragma unroll
        for (int off = 1; off < 16; off <<= 1) {
            int t = __shfl_up(s, off);
            if (lane >= off) s += t;
        }
        wsum[lane] = s;
    }
    __syncthreads();
    if (wid > 0) v += wsum[wid - 1];
    if (i < n) start[i + 1] = v;
    if (tid == 1023) totals[cb] = v;
}

// ------------- scan phase 2 -------------
__global__ void scan_totals(
    const int* __restrict__ totals_e, int* __restrict__ boff_e,
    const int* __restrict__ totals_n, int* __restrict__ boff_n,
    int* __restrict__ start_e, int* __restrict__ start_n)
{
    int lane = threadIdx.x;
    int ve0 = (lane < EBLK) ? totals_e[lane] : 0;
    int ve = ve0;
    #pragma unroll
    for (int off = 1; off < 64; off <<= 1) {
        int t = __shfl_up(ve, off);
        if (lane >= off) ve += t;
    }
    if (lane < EBLK) boff_e[lane] = ve - ve0;
    int vn0 = (lane < NBLK) ? totals_n[lane] : 0;
    int vn = vn0;
    #pragma unroll
    for (int off = 1; off < 64; off <<= 1) {
        int t = __shfl_up(vn, off);
        if (lane >= off) vn += t;
    }
    if (lane < NBLK) boff_n[lane] = vn - vn0;
    if (lane == 0) { start_e[0] = 0; start_n[0] = 0; }
}

// ------------- scan phase 3 -------------
__global__ void scan_add(
    int* __restrict__ start_e, const int* __restrict__ boff_e,
    int* __restrict__ start_n, const int* __restrict__ boff_n)
{
    int id = blockIdx.x * 256 + threadIdx.x;
    if (id < M_EDGES) start_e[id + 1] += boff_e[id >> 10];
    else if (id < M_EDGES + N_NODES) {
        int j = id - M_EDGES;
        start_n[j + 1] += boff_n[j >> 10];
    }
}

// ------------- init cursors + rnorm -------------
__global__ void initcur_kernel(const int* __restrict__ start_e, const int* __restrict__ start_n,
                               const float* __restrict__ esum,
                               int* __restrict__ cur_e, int* __restrict__ cur_n,
                               float* __restrict__ rnorm)
{
    int i = blockIdx.x * blockDim.x + threadIdx.x;
    if (i < M_EDGES) cur_e[i] = start_e[i];
    if (i < N_NODES) {
        cur_n[i] = start_n[i];
        rnorm[i] = 1.f / (esum[i] + 1e-16f);
    }
}

// ------------- CSR scatter + normalized attention an[e] -------------
__global__ void scatter_kernel(
    const int* __restrict__ node_idx, const int* __restrict__ edge_idx,
    const float* __restrict__ ealpha, const float* __restrict__ rnorm,
    int* __restrict__ cur_e, int* __restrict__ cur_n,
    int* __restrict__ list_e, int* __restrict__ list_n, float* __restrict__ an)
{
    int e = blockIdx.x * blockDim.x + threadIdx.x;
    if (e >= N_INC) return;
    int n = node_idx[e];
    int p = atomicAdd(cur_e + edge_idx[e], 1);
    list_e[p] = e;
    int q = atomicAdd(cur_n + n, 1);
    list_n[q] = e;
    an[e] = ealpha[e] * rnorm[n];
}

// ------------- stage 1: gather bf16 xw per hyperedge -> bf16 edge_feat (binv uniform) -------------
__global__ __launch_bounds__(256) void stage1_kernel(
    const ushort* __restrict__ xwb, const int* __restrict__ node_idx,
    const float* __restrict__ an, const int* __restrict__ start_e,
    const int* __restrict__ list_e, ushort* __restrict__ edge_feat)
{
    int h = blockIdx.x * 4 + (threadIdx.x >> 6);
    if (h >= M_EDGES) return;
    int lane = threadIdx.x & 63;
    int j0 = start_e[h], j1 = start_e[h + 1];
    float4 acc = make_float4(0.f, 0.f, 0.f, 0.f);
    for (int base = j0; base < j1; base += 64) {
        int cnt = min(64, j1 - base);
        float wv = 0.f; int nv = 0;
        if (lane < cnt) { int e = list_e[base + lane]; wv = an[e]; nv = node_idx[e]; }
        int jj = 0;
        for (; jj + 2 <= cnt; jj += 2) {
            float wg0 = __shfl(wv, jj);     int n0 = __shfl(nv, jj);
            float wg1 = __shfl(wv, jj + 1); int n1 = __shfl(nv, jj + 1);
            uint2 p0 = *(const uint2*)(xwb + (size_t)n0 * DIM + lane * 4);
            uint2 p1 = *(const uint2*)(xwb + (size_t)n1 * DIM + lane * 4);
            float4 v0 = unp4(p0), v1 = unp4(p1);
            acc.x += wg0 * v0.x + wg1 * v1.x;
            acc.y += wg0 * v0.y + wg1 * v1.y;
            acc.z += wg0 * v0.z + wg1 * v1.z;
            acc.w += wg0 * v0.w + wg1 * v1.w;
        }
        if (jj < cnt) {
            float wg = __shfl(wv, jj); int n0 = __shfl(nv, jj);
            float4 v = unp4(*(const uint2*)(xwb + (size_t)n0 * DIM + lane * 4));
            acc.x += wg * v.x; acc.y += wg * v.y;
            acc.z += wg * v.z; acc.w += wg * v.w;
        }
    }
    float binv = (j1 > j0) ? 1.f / (float)(j1 - j0) : 0.f;
    uint2 p;
    p.x = bf16rn(acc.x * binv) | (bf16rn(acc.y * binv) << 16);
    p.y = bf16rn(acc.z * binv) | (bf16rn(acc.w * binv) << 16);
    *(uint2*)(edge_feat + (size_t)h * DIM + lane * 4) = p;
}

// ------------- stage 2: gather bf16 edge_feat per node (dinv uniform), + bias -> f32 out -------------
__global__ __launch_bounds__(256) void stage2_kernel(
    const ushort* __restrict__ edge_feat, const int* __restrict__ edge_idx,
    const float* __restrict__ an, const int* __restrict__ start_n,
    const int* __restrict__ list_n, const float* __restrict__ bias,
    float* __restrict__ out)
{
    int n = blockIdx.x * 4 + (threadIdx.x >> 6);
    if (n >= N_NODES) return;
    int lane = threadIdx.x & 63;
    int j0 = start_n[n], j1 = start_n[n + 1];
    float4 acc = make_float4(0.f, 0.f, 0.f, 0.f);
    for (int base = j0; base < j1; base += 64) {
        int cnt = min(64, j1 - base);
        float wv = 0.f; int hv = 0;
        if (lane < cnt) { int e = list_n[base + lane]; wv = an[e]; hv = edge_idx[e]; }
        int jj = 0;
        for (; jj + 2 <= cnt; jj += 2) {
            float wg0 = __shfl(wv, jj);     int h0 = __shfl(hv, jj);
            float wg1 = __shfl(wv, jj + 1); int h1 = __shfl(hv, jj + 1);
            uint2 p0 = *(const uint2*)(edge_feat + (size_t)h0 * DIM + lane * 4);
            uint2 p1 = *(const uint2*)(edge_feat + (size_t)h1 * DIM + lane * 4);
            float4 v0 = unp4(p0), v1 = unp4(p1);
            acc.x += wg0 * v0.x + wg1 * v1.x;
            acc.y += wg0 * v0.y + wg1 * v1.y;
            acc.z += wg0 * v0.z + wg1 * v1.z;
            acc.w += wg0 * v0.w + wg1 * v1.w;
        }
        if (jj < cnt) {
            float wg = __shfl(wv, jj); int h0 = __shfl(hv, jj);
            float4 v = unp4(*(const uint2*)(edge_feat + (size_t)h0 * DIM + lane * 4));
            acc.x += wg * v.x; acc.y += wg * v.y;
            acc.z += wg * v.z; acc.w += wg * v.w;
        }
    }
    float dinv = (j1 > j0) ? 1.f / (float)(j1 - j0) : 0.f;
    float4 b = *(const float4*)(bias + lane * 4);
    acc.x = fmaf(acc.x, dinv, b.x); acc.y = fmaf(acc.y, dinv, b.y);
    acc.z = fmaf(acc.z, dinv, b.z); acc.w = fmaf(acc.w, dinv, b.w);
    *(float4*)(out + (size_t)n * DIM + lane * 4) = acc;
}

// ------------- BN column stats: float4 + LDS cross-wave reduce -------------
__global__ __launch_bounds__(256) void stats_kernel(
    const float* __restrict__ out, float* __restrict__ stats)
{
    __shared__ float lsum[4][256], lsq[4][256];
    int tid = threadIdx.x, lane = tid & 63, w = tid >> 6;
    int c4 = lane * 4;
    int rows_per = (N_NODES + gridDim.x - 1) / gridDim.x;
    int r0 = blockIdx.x * rows_per;
    int r1 = min(r0 + rows_per, N_NODES);
    float4 s = make_float4(0.f, 0.f, 0.f, 0.f);
    float4 q = make_float4(0.f, 0.f, 0.f, 0.f);
    for (int r = r0 + w; r < r1; r += 4) {
        float4 v = *(const float4*)(out + (size_t)r * DIM + c4);
        s.x += v.x; s.y += v.y; s.z += v.z; s.w += v.w;
        q.x += v.x * v.x; q.y += v.y * v.y; q.z += v.z * v.z; q.w += v.w * v.w;
    }
    *(float4*)&lsum[w][c4] = s;
    *(float4*)&lsq[w][c4] = q;
    __syncthreads();
    if (w == 0) {
        #pragma unroll
        for (int i = 1; i < 4; ++i) {
            s.x += lsum[i][c4]; s.y += lsum[i][c4 + 1]; s.z += lsum[i][c4 + 2]; s.w += lsum[i][c4 + 3];
            q.x += lsq[i][c4];  q.y += lsq[i][c4 + 1];  q.z += lsq[i][c4 + 2];  q.w += lsq[i][c4 + 3];
        }
        atomicAdd(stats + c4 + 0, s.x); atomicAdd(stats + c4 + 1, s.y);
        atomicAdd(stats + c4 + 2, s.z); atomicAdd(stats + c4 + 3, s.w);
        atomicAdd(stats + DIM + c4 + 0, q.x); atomicAdd(stats + DIM + c4 + 1, q.y);
        atomicAdd(stats + DIM + c4 + 2, q.z); atomicAdd(stats + DIM + c4 + 3, q.w);
    }
}

// ------------- BN prep: per-column scale/shift -------------
__global__ void bnprep_kernel(
    const float* __restrict__ stats, const float* __restrict__ gamma,
    const float* __restrict__ beta, float* __restrict__ scale, float* __restrict__ shift)
{
    int c = threadIdx.x;
    float mu = stats[c] * (1.f / N_NODES);
    float var = stats[DIM + c] * (1.f / N_NODES) - mu * mu;
    float sc = gamma[c] * rsqrtf(var + BN_EPS);
    scale[c] = sc;
    shift[c] = beta[c] - mu * sc;
}

// ------------- BN apply + ELU, streaming float4 -------------
__global__ __launch_bounds__(256) void bn_kernel(
    float* __restrict__ out, const float* __restrict__ scale, const float* __restrict__ shift)
{
    int idx = blockIdx.x * 256 + threadIdx.x;       // N*DIM/4 threads
    int c4 = (idx & 63) * 4;
    float4 sc = *(const float4*)(scale + c4);
    float4 sh = *(const float4*)(shift + c4);
    float4 v = ((float4*)out)[idx];
    v.x = fmaf(v.x, sc.x, sh.x); v.y = fmaf(v.y, sc.y, sh.y);
    v.z = fmaf(v.z, sc.z, sh.z); v.w = fmaf(v.w, sc.w, sh.w);
    v.x = v.x > 0.f ? v.x : __expf(v.x) - 1.f;
    v.y = v.y > 0.f ? v.y : __expf(v.y) - 1.f;
    v.z = v.z > 0.f ? v.z : __expf(v.z) - 1.f;
    v.w = v.w > 0.f ? v.w : __expf(v.w) - 1.f;
    ((float4*)out)[idx] = v;
}

extern "C" void kernel_launch(void* const* d_in, const int* in_sizes, int n_in,
                              void* d_out, int out_size, void* d_ws, size_t ws_size,
                              hipStream_t stream)
{
    const float* x        = (const float*)d_in[0];
    const int*   node_idx = (const int*)d_in[1];
    const int*   edge_idx = (const int*)d_in[2];
    const float* W        = (const float*)d_in[4];
    const float* att      = (const float*)d_in[5];
    const float* bias     = (const float*)d_in[6];
    const float* gamma    = (const float*)d_in[7];
    const float* beta     = (const float*)d_in[8];
    float* out = (float*)d_out;
    ushort* xwb = (ushort*)d_out;     // bf16 xw in first 25.6 MB of d_out; overwritten by stage2

    ushort* edge_feat = (ushort*)d_ws;                          // M*DIM bf16
    // ---- zeroed block (contiguous) ----
    int*   cnt_e   = (int*)(edge_feat + (size_t)M_EDGES * DIM); // M
    int*   cnt_n   = cnt_e + M_EDGES;                           // N
    float* stats   = (float*)(cnt_n + N_NODES);                 // 2*DIM
    float* s1      = stats + 2 * DIM;                           // N
    float* s2      = s1 + N_NODES;                              // N
    float* esum    = s2 + N_NODES;                              // N
    // ---- not zeroed ----
    float* ealpha  = esum + N_NODES;                            // E
    float* an      = ealpha + N_INC;                            // E
    float* rnorm   = an + N_INC;                                // N
    int*   start_e = (int*)(rnorm + N_NODES);                   // M+1
    int*   start_n = start_e + M_EDGES + 1;                     // N+1
    int*   cur_e   = start_n + N_NODES + 1;                     // M
    int*   cur_n   = cur_e + M_EDGES;                           // N
    int*   list_e  = cur_n + N_NODES;                           // E
    int*   list_n  = list_e + N_INC;                            // E
    ushort* WT     = (ushort*)(list_n + N_INC);                 // 256*256 bf16
    int*   totals_e = (int*)(WT + 256 * 256);                   // EBLK
    int*   boff_e   = totals_e + EBLK;                          // EBLK
    int*   totals_n = boff_e + EBLK;                            // NBLK
    int*   boff_n   = totals_n + NBLK;                          // NBLK
    float* scale    = (float*)(boff_n + NBLK);                  // DIM
    float* shift    = scale + DIM;                              // DIM

    hipMemsetAsync(cnt_e, 0,
        (size_t)(M_EDGES + N_NODES + 2 * DIM + 3 * N_NODES) * 4, stream);

    wt_kernel<<<256, 256, 0, stream>>>(W, WT);
    gemm_mfma<<<dim3((N_NODES + BMM - 1) / BMM, DIM / BNN), 256, 0, stream>>>(x, WT, att, xwb, s1, s2);
    alpha_kernel<<<(N_INC + 255) / 256, 256, 0, stream>>>(node_idx, edge_idx, s1, s2, ealpha, esum, cnt_n, cnt_e);
    scan_partial<<<EBLK + NBLK, 1024, 0, stream>>>(cnt_e, start_e, totals_e, cnt_n, start_n, totals_n);
    scan_totals<<<1, 64, 0, stream>>>(totals_e, boff_e, totals_n, boff_n, start_e, start_n);
    scan_add<<<(M_EDGES + N_NODES + 255) / 256, 256, 0, stream>>>(start_e, boff_e, start_n, boff_n);
    initcur_kernel<<<(N_NODES + 255) / 256, 256, 0, stream>>>(start_e, start_n, esum, cur_e, cur_n, rnorm);
    scatter_kernel<<<(N_INC + 255) / 256, 256, 0, stream>>>(node_idx, edge_idx, ealpha, rnorm, cur_e, cur_n, list_e, list_n, an);
    stage1_kernel<<<(M_EDGES + 3) / 4, 256, 0, stream>>>(xwb, node_idx, an, start_e, list_e, edge_feat);
    stage2_kernel<<<(N_NODES + 3) / 4, 256, 0, stream>>>(edge_feat, edge_idx, an, start_n, list_n, bias, out);
    stats_kernel<<<128, 256, 0, stream>>>(out, stats);
    bnprep_kernel<<<1, 256, 0, stream>>>(stats, gamma, beta, scale, shift);
    bn_kernel<<<N_NODES * DIM / 4 / 256, 256, 0, stream>>>(out, scale, shift);
}